// Round 8
// baseline (267.264 us; speedup 1.0000x reference)
//
#include <hip/hip_runtime.h>
#include <cmath>

// ---------------- problem constants ----------------
constexpr int kN  = 10000;   // nodes
constexpr int kE  = 160000;  // edges
constexpr int kP  = 4000;    // physical edges
constexpr int kND = 8;       // input node feat dim
constexpr int kH  = 4;       // heads
constexpr int kC  = 64;      // channels per head
constexpr int kD1 = kH * kC; // 256
constexpr int kEFS  = 2 * kD1 + 3; // 515 real concat dim
constexpr int kEFSP = 544;         // padded to 17*32 for BK=32 MFMA loop

constexpr unsigned kTblSize = 1u << 19;
constexpr unsigned kTblMask = kTblSize - 1;
constexpr unsigned kEmpty   = 0xFFFFFFFFu;

typedef __attribute__((ext_vector_type(8))) short bf16x8;
typedef __attribute__((ext_vector_type(4))) float f32x4;

__device__ __forceinline__ unsigned short f2bf(float f) {
  unsigned u = __float_as_uint(f);
  unsigned r = (u + 0x7FFFu + ((u >> 16) & 1u)) >> 16;
  return (unsigned short)r;
}
__device__ __forceinline__ float bf2f(unsigned short u) {
  return __uint_as_float(((unsigned)u) << 16);
}

__device__ __forceinline__ unsigned hash_u32(unsigned k) {
  k *= 2654435761u;
  k ^= k >> 16;
  return k & kTblMask;
}

// async global->LDS 16B per lane; LDS dest must be wave-uniform base + lane*16
__device__ __forceinline__ void async_ld16(const void* g, void* l) {
  __builtin_amdgcn_global_load_lds((const __attribute__((address_space(1))) void*)g,
                                   (__attribute__((address_space(3))) void*)l,
                                   16, 0, 0);
}

// ---------------- mega kernel 1: layer1 dual proj + hist/hash + weight cvt
constexpr int kGemmBX    = (kN + 63) / 64;       // 157
constexpr int kGemmBlk   = kGemmBX * 8;          // 1256
constexpr int kHistBlk   = (kE + 255) / 256;     // 625
constexpr int kCvtElems  = 2 * 256 * 256 + 64 * kEFSP + 64 * 256; // 182272
constexpr int kCvtBlk    = (kCvtElems + 255) / 256; // 712
constexpr int kMegaBlk   = kGemmBlk + kHistBlk + kCvtBlk;

__launch_bounds__(256)
__global__ void mega1_k(const float* __restrict__ x,
                        const float* __restrict__ Wl1, const float* __restrict__ bl1,
                        const float* __restrict__ Wr1, const float* __restrict__ br1,
                        unsigned short* __restrict__ xl_bf, float* __restrict__ xr,
                        const int* __restrict__ src, const int* __restrict__ dst,
                        int* __restrict__ counts, unsigned* __restrict__ tbl,
                        const float* __restrict__ Wl2, const float* __restrict__ Wr2,
                        const float* __restrict__ Wq1, const float* __restrict__ Wn1,
                        unsigned short* __restrict__ Wl2t, unsigned short* __restrict__ Wr2t,
                        unsigned short* __restrict__ Wq1t, unsigned short* __restrict__ Wn1t) {
  __shared__ __align__(16) float s_a[8][68];
  __shared__ __align__(16) float s_w[8][64];
  int bi = blockIdx.x;
  int tid = threadIdx.x;
  if (bi < kGemmBlk) {
    // ---- layer-1 dual projection, K=8 ----
    int bx = bi % kGemmBX, by = bi / kGemmBX;
    int r0 = bx * 64;
    const float* W; const float* bb; int isBF;
    if (by < 4) { W = Wl1; bb = bl1; isBF = 1; }
    else        { W = Wr1; bb = br1; isBF = 0; by -= 4; }
    int cbase = by * 64;
#pragma unroll
    for (int f = tid; f < 512; f += 256) { // A: 64 rows x 8 k (coalesced)
      int rr = f >> 3, kk = f & 7;
      int r = r0 + rr;
      s_a[kk][rr] = (r < kN) ? x[(size_t)r * kND + kk] : 0.f;
    }
#pragma unroll
    for (int f = tid; f < 512; f += 256) { // W: 8 k x 64 cols
      int kk = f >> 6, cc = f & 63;
      s_w[kk][cc] = W[(size_t)kk * kD1 + cbase + cc];
    }
    __syncthreads();
    int tx = tid & 15, ty = tid >> 4;
    float acc[4][4];
#pragma unroll
    for (int i = 0; i < 4; i++)
#pragma unroll
      for (int j = 0; j < 4; j++) acc[i][j] = 0.f;
#pragma unroll
    for (int kk = 0; kk < 8; kk++) {
      float4 av = *(const float4*)&s_a[kk][ty * 4];
      float4 wv = *(const float4*)&s_w[kk][tx * 4];
      float a4[4] = {av.x, av.y, av.z, av.w};
      float w4[4] = {wv.x, wv.y, wv.z, wv.w};
#pragma unroll
      for (int i = 0; i < 4; i++)
#pragma unroll
        for (int j = 0; j < 4; j++) acc[i][j] = fmaf(a4[i], w4[j], acc[i][j]);
    }
    int c = cbase + tx * 4;
    float b4[4] = {bb[c], bb[c + 1], bb[c + 2], bb[c + 3]};
#pragma unroll
    for (int i = 0; i < 4; i++) {
      int r = r0 + ty * 4 + i;
      if (r < kN) {
        float u0 = acc[i][0] + b4[0], u1 = acc[i][1] + b4[1];
        float u2 = acc[i][2] + b4[2], u3 = acc[i][3] + b4[3];
        if (isBF) {
          ushort4 v;
          v.x = f2bf(u0); v.y = f2bf(u1); v.z = f2bf(u2); v.w = f2bf(u3);
          *(ushort4*)&xl_bf[(size_t)r * kD1 + c] = v;
        } else {
          float4 v = {u0, u1, u2, u3};
          *(float4*)&xr[(size_t)r * kD1 + c] = v;
        }
      }
    }
  } else if (bi < kGemmBlk + kHistBlk) {
    // ---- histogram (counts init -1 via 0xFF memset) + hash insert ----
    int e = (bi - kGemmBlk) * 256 + tid;
    if (e >= kE) return;
    int d = dst[e];
    atomicAdd(&counts[d], 1);
    unsigned key = (unsigned)src[e] * (unsigned)kN + (unsigned)d;
    unsigned h = hash_u32(key);
    for (;;) {
      unsigned prev = atomicCAS(&tbl[2 * h], kEmpty, key);
      if (prev == kEmpty || prev == key) {
        atomicMin(&tbl[2 * h + 1], (unsigned)e);
        return;
      }
      h = (h + 1) & kTblMask;
    }
  } else {
    // ---- weight transpose + fp32->bf16 ----
    const int s0 = 256 * 256, s1 = 2 * s0, s2 = s1 + 64 * kEFSP, s3 = s2 + 64 * 256;
    int idx = (bi - kGemmBlk - kHistBlk) * 256 + tid;
    if (idx < s0) {
      int n = idx >> 8, k = idx & 255;
      Wl2t[idx] = f2bf(Wl2[(size_t)k * 256 + n]);
    } else if (idx < s1) {
      int q = idx - s0;
      int n = q >> 8, k = q & 255;
      Wr2t[q] = f2bf(Wr2[(size_t)k * 256 + n]);
    } else if (idx < s2) {
      int q = idx - s1;
      int n = q / kEFSP, k = q - n * kEFSP;
      Wq1t[q] = (k < kEFS) ? f2bf(Wq1[(size_t)k * 64 + n]) : (unsigned short)0;
    } else if (idx < s3) {
      int q = idx - s2;
      int n = q >> 8, k = q & 255;
      Wn1t[q] = f2bf(Wn1[(size_t)k * 64 + n]);
    }
  }
}

// ---------------- single-block exclusive scan: 1024 thr x 10 counts each ---
__launch_bounds__(1024)
__global__ void scan_k(const int* __restrict__ counts, int* __restrict__ row_ptr,
                       int* __restrict__ cursor) {
  __shared__ int wsum[16];
  int tid = threadIdx.x;
  int lane = tid & 63, w = tid >> 6;
  int base = tid * 10;
  int v[10];
  int tot = 0;
#pragma unroll
  for (int i = 0; i < 10; i++) {
    int idx = base + i;
    v[i] = (idx < kN) ? (counts[idx] + 1) : 0; // +1: counts init was -1
    tot += v[i];
  }
  int inc = tot;
#pragma unroll
  for (int o = 1; o < 64; o <<= 1) {
    int t = __shfl_up(inc, o);
    if (lane >= o) inc += t;
  }
  if (lane == 63) wsum[w] = inc;
  __syncthreads();
  int woff = 0;
  for (int q = 0; q < w; q++) woff += wsum[q];
  int run = woff + inc - tot;
#pragma unroll
  for (int i = 0; i < 10; i++) {
    int idx = base + i;
    if (idx < kN) { row_ptr[idx] = run; cursor[idx] = run; }
    run += v[i];
  }
  if (tid == 0) row_ptr[kN] = kE;
}

// scatter edge records {src, ea0, ea1, ea2} into CSR-by-dst order
__global__ void scatter_k(const int* __restrict__ src, const int* __restrict__ dst,
                          const float* __restrict__ edge_attr,
                          int* __restrict__ cursor, float4* __restrict__ rec) {
  int e = blockIdx.x * blockDim.x + threadIdx.x;
  if (e >= kE) return;
  int d = dst[e];
  int pos = atomicAdd(&cursor[d], 1);
  float4 r;
  r.x = __int_as_float(src[e]);
  r.y = edge_attr[e * 3 + 0];
  r.z = edge_attr[e * 3 + 1];
  r.w = edge_attr[e * 3 + 2];
  rec[pos] = r;
}

// ---------------- bf16 MFMA GEMM with async global->LDS staging ------------
// Staging map: thread tid stages 16B at LDS byte offset tid*16 (wave-uniform
// base + lane*16 -> legal for global_load_lds). Tail rows (r>=M) load garbage
// that only feeds discarded output rows.
template <int ACT, int BF0, int BF1>
__launch_bounds__(256)
__global__ void mgemm_k(const unsigned short* __restrict__ in, int M, int Kp,
                        const unsigned short* __restrict__ Wt0,
                        const float* __restrict__ b0, void* __restrict__ out0,
                        const unsigned short* __restrict__ Wt1,
                        const float* __restrict__ b1, void* __restrict__ out1,
                        int N, int nby) {
  __shared__ __align__(16) short s_a[64][32];
  __shared__ __align__(16) short s_b[64][32];
  int tid = threadIdx.x;
  int l = tid & 63, w = tid >> 6;
  int r0 = blockIdx.x * 64;
  int by = blockIdx.y;
  const unsigned short* Wt = Wt0; const float* bb = b0; void* outv = out0; int bf = BF0;
  if (by >= nby) { Wt = Wt1; bb = b1; outv = out1; bf = BF1; by -= nby; }
  int cbase = by * 64;

  int sr = tid >> 2;
  int skc = tid & 3;

  f32x4 acc[4];
#pragma unroll
  for (int c = 0; c < 4; c++) acc[c] = (f32x4){0.f, 0.f, 0.f, 0.f};

  int m_frag = l & 15, quad = l >> 4;
  char* la = (char*)&s_a[0][0] + tid * 16;
  char* lb = (char*)&s_b[0][0] + tid * 16;
  const unsigned short* ga = &in[(size_t)(r0 + sr) * Kp + skc * 8];
  const unsigned short* gb = &Wt[(size_t)(cbase + sr) * Kp + skc * 8];

  for (int k0 = 0; k0 < Kp; k0 += 32) {
    async_ld16(ga + k0, la);
    async_ld16(gb + k0, lb);
    __syncthreads();
    bf16x8 af = *(const bf16x8*)&s_a[w * 16 + m_frag][quad * 8];
#pragma unroll
    for (int c = 0; c < 4; c++) {
      bf16x8 bfr = *(const bf16x8*)&s_b[c * 16 + m_frag][quad * 8];
      acc[c] = __builtin_amdgcn_mfma_f32_16x16x32_bf16(af, bfr, acc[c], 0, 0, 0);
    }
    __syncthreads();
  }

#pragma unroll
  for (int c = 0; c < 4; c++) {
    int col = cbase + c * 16 + m_frag;
    float bv = bb[col];
#pragma unroll
    for (int i = 0; i < 4; i++) {
      int r = r0 + w * 16 + quad * 4 + i;
      if (r < M) {
        float u = acc[c][i] + bv;
        if (ACT == 1) u = (u > 0.f) ? u : expm1f(u);
        if (bf) ((unsigned short*)outv)[(size_t)r * N + col] = f2bf(u);
        else    ((float*)outv)[(size_t)r * N + col] = u;
      }
    }
  }
}

// ---------------- GATv2 layer: block = node, 4 waves split the edge list ---
__launch_bounds__(256)
__global__ void gat_k(const unsigned short* __restrict__ xl_bf, const float* __restrict__ xr,
                      const int* __restrict__ row_ptr, const float4* __restrict__ rec,
                      const float* __restrict__ We, const float* __restrict__ att,
                      const float* __restrict__ bias, unsigned short* __restrict__ out_bf) {
  __shared__ float sA[4][4][64]; // [wave][channel][lane] - conflict-free
  __shared__ float sS[4][64];
  int n = blockIdx.x;
  int tid = threadIdx.x;
  int l = tid & 63, w = tid >> 6;
  int c0 = (l >> 4) * kC + (l & 15) * 4;

  float4 xr_c = *(const float4*)&xr[(size_t)n * kD1 + c0];
  float4 we0 = *(const float4*)&We[0 * kD1 + c0];
  float4 we1 = *(const float4*)&We[1 * kD1 + c0];
  float4 we2 = *(const float4*)&We[2 * kD1 + c0];
  float4 at4 = *(const float4*)&att[c0];

  int row = row_ptr[n], end = row_ptr[n + 1];
  float S = 0.f;
  float A0 = 0.f, A1 = 0.f, A2 = 0.f, A3 = 0.f;

  // 3-deep software pipeline over this wave's edge subset (stride 4)
  int k = row + w;
  float4 rA, rB, rC; ushort4 xA, xB, xC;
  if (k < end) {
    rA = rec[k];
    xA = *(const ushort4*)&xl_bf[(size_t)__float_as_int(rA.x) * kD1 + c0];
  }
  if (k + 4 < end) {
    rB = rec[k + 4];
    xB = *(const ushort4*)&xl_bf[(size_t)__float_as_int(rB.x) * kD1 + c0];
  }
  if (k + 8 < end) {
    rC = rec[k + 8];
    xC = *(const ushort4*)&xl_bf[(size_t)__float_as_int(rC.x) * kD1 + c0];
  }
  for (; k < end; k += 4) {
    float4 rc = rA; ushort4 xc = xA;
    rA = rB; xA = xB;
    rB = rC; xB = xC;
    if (k + 12 < end) {
      rC = rec[k + 12];
      xC = *(const ushort4*)&xl_bf[(size_t)__float_as_int(rC.x) * kD1 + c0];
    }
    float x0 = bf2f(xc.x), x1 = bf2f(xc.y), x2 = bf2f(xc.z), x3 = bf2f(xc.w);
    float m0 = x0 + xr_c.x + fmaf(rc.y, we0.x, fmaf(rc.z, we1.x, rc.w * we2.x));
    float m1 = x1 + xr_c.y + fmaf(rc.y, we0.y, fmaf(rc.z, we1.y, rc.w * we2.y));
    float m2 = x2 + xr_c.z + fmaf(rc.y, we0.z, fmaf(rc.z, we1.z, rc.w * we2.z));
    float m3 = x3 + xr_c.w + fmaf(rc.y, we0.w, fmaf(rc.z, we1.w, rc.w * we2.w));
    m0 = fmaxf(m0, 0.2f * m0); m1 = fmaxf(m1, 0.2f * m1);
    m2 = fmaxf(m2, 0.2f * m2); m3 = fmaxf(m3, 0.2f * m3);
    float t = fmaf(m0, at4.x, fmaf(m1, at4.y, fmaf(m2, at4.z, m3 * at4.w)));
    t += __shfl_xor(t, 1);
    t += __shfl_xor(t, 2);
    t += __shfl_xor(t, 4);
    t += __shfl_xor(t, 8); // reduce within 16-lane head group
    float wgt = __expf(t); // logits O(1): no max-subtraction needed
    S += wgt;
    A0 = fmaf(wgt, x0, A0); A1 = fmaf(wgt, x1, A1);
    A2 = fmaf(wgt, x2, A2); A3 = fmaf(wgt, x3, A3);
  }
  sA[w][0][l] = A0; sA[w][1][l] = A1; sA[w][2][l] = A2; sA[w][3][l] = A3;
  sS[w][l] = S;
  __syncthreads();
  if (w == 0) {
    float St = sS[0][l] + sS[1][l] + sS[2][l] + sS[3][l];
    float T0 = sA[0][0][l] + sA[1][0][l] + sA[2][0][l] + sA[3][0][l];
    float T1 = sA[0][1][l] + sA[1][1][l] + sA[2][1][l] + sA[3][1][l];
    float T2 = sA[0][2][l] + sA[1][2][l] + sA[2][2][l] + sA[3][2][l];
    float T3 = sA[0][3][l] + sA[1][3][l] + sA[2][3][l] + sA[3][3][l];
    float inv = 1.f / (St + 1e-16f);
    float4 b4 = *(const float4*)&bias[c0];
    float u0 = fmaf(T0, inv, b4.x), u1 = fmaf(T1, inv, b4.y);
    float u2 = fmaf(T2, inv, b4.z), u3 = fmaf(T3, inv, b4.w);
    u0 = (u0 > 0.f) ? u0 : expm1f(u0);
    u1 = (u1 > 0.f) ? u1 : expm1f(u1);
    u2 = (u2 > 0.f) ? u2 : expm1f(u2);
    u3 = (u3 > 0.f) ? u3 : expm1f(u3);
    ushort4 ov;
    ov.x = f2bf(u0); ov.y = f2bf(u1); ov.z = f2bf(u2); ov.w = f2bf(u3);
    *(ushort4*)&out_bf[(size_t)n * kD1 + c0] = ov;
  }
}

// ---------------- fused heads: edge head blocks then node head blocks ------
constexpr int kEheadBlk = (kP + 63) / 64; // 63
constexpr int kNheadBlk = (kN + 63) / 64; // 157

__launch_bounds__(256)
__global__ void heads_k(const unsigned short* __restrict__ h_bf, const int* __restrict__ pe,
                        const float* __restrict__ edge_attr, const unsigned* __restrict__ tbl,
                        const unsigned short* __restrict__ Wqt, const float* __restrict__ bq1,
                        const float* __restrict__ Wq2, const float* __restrict__ bq2,
                        const float* __restrict__ Wq3, const float* __restrict__ bq3,
                        const unsigned short* __restrict__ Wnt, const float* __restrict__ bn1,
                        const float* __restrict__ Wn2, const float* __restrict__ bn2,
                        const float* __restrict__ Wn3, const float* __restrict__ bn3,
                        float* __restrict__ out_e, float* __restrict__ out_n) {
  __shared__ union {
    struct { short a[64][32]; short b[64][32]; } st;
    float u[64][65];
  } sm;
  __shared__ int s_i[64], s_j[64];
  __shared__ unsigned short s_ea[64][4];
  int tid = threadIdx.x;
  int l = tid & 63, w = tid >> 6;
  int sr = tid >> 2, skc = tid & 3;
  int m_frag = l & 15, quad = l >> 4;
  char* la = (char*)&sm.st.a[0][0] + tid * 16;
  char* lb = (char*)&sm.st.b[0][0] + tid * 16;

  f32x4 acc[4];
#pragma unroll
  for (int c = 0; c < 4; c++) acc[c] = (f32x4){0.f, 0.f, 0.f, 0.f};

  if (blockIdx.x < kEheadBlk) {
    // ================== edge head ==================
    int r0 = blockIdx.x * 64;
    if (tid < 64) {
      int p = r0 + tid;
      int i = 0, j = 0;
      unsigned short e0 = 0, e1 = 0, e2 = 0;
      if (p < kP) {
        i = pe[p * 2 + 0]; j = pe[p * 2 + 1];
        unsigned best = kEmpty;
        unsigned keys[2] = { (unsigned)i * (unsigned)kN + (unsigned)j,
                             (unsigned)j * (unsigned)kN + (unsigned)i };
        for (int q = 0; q < 2; q++) {
          unsigned key = keys[q];
          unsigned hsh = hash_u32(key);
          for (;;) {
            unsigned k2 = tbl[2 * hsh];
            if (k2 == kEmpty) break;
            if (k2 == key) {
              unsigned v = tbl[2 * hsh + 1];
              if (v < best) best = v;
              break;
            }
            hsh = (hsh + 1) & kTblMask;
          }
        }
        if (best != kEmpty) {
          e0 = f2bf(edge_attr[best * 3 + 0]);
          e1 = f2bf(edge_attr[best * 3 + 1]);
          e2 = f2bf(edge_attr[best * 3 + 2]);
        }
      }
      s_i[tid] = i; s_j[tid] = j;
      s_ea[tid][0] = e0; s_ea[tid][1] = e1; s_ea[tid][2] = e2; s_ea[tid][3] = 0;
    }
    __syncthreads();
    int ri = s_i[sr], rj = s_j[sr];

    for (int k0 = 0; k0 < kEFSP; k0 += 32) {
      int gk = k0 + skc * 8;
      if (k0 < 256) {
        async_ld16(&h_bf[(size_t)ri * kD1 + gk], la);
      } else if (k0 < 512) {
        async_ld16(&h_bf[(size_t)rj * kD1 + (gk - 256)], la);
      } else {
        bf16x8 av = (bf16x8){0, 0, 0, 0, 0, 0, 0, 0};
        if (gk == 512) {
          av[0] = (short)s_ea[sr][0];
          av[1] = (short)s_ea[sr][1];
          av[2] = (short)s_ea[sr][2];
        }
        *(bf16x8*)&sm.st.a[sr][skc * 8] = av;
      }
      async_ld16(&Wqt[(size_t)sr * kEFSP + k0 + skc * 8], lb);
      __syncthreads();
      bf16x8 af = *(const bf16x8*)&sm.st.a[w * 16 + m_frag][quad * 8];
#pragma unroll
      for (int c = 0; c < 4; c++) {
        bf16x8 bfr = *(const bf16x8*)&sm.st.b[c * 16 + m_frag][quad * 8];
        acc[c] = __builtin_amdgcn_mfma_f32_16x16x32_bf16(af, bfr, acc[c], 0, 0, 0);
      }
      __syncthreads();
    }

#pragma unroll
    for (int c = 0; c < 4; c++) {
      int col = c * 16 + m_frag;
      float bv = bq1[col];
#pragma unroll
      for (int i = 0; i < 4; i++) {
        float u = acc[c][i] + bv;
        u = (u > 0.f) ? u : expm1f(u);
        sm.u[w * 16 + quad * 4 + i][col] = u;
      }
    }
    __syncthreads();

    int c2 = tid & 31, rb = (tid >> 5) * 8;
    float a2[8];
#pragma unroll
    for (int i = 0; i < 8; i++) a2[i] = 0.f;
    for (int k = 0; k < 64; k++) {
      float wv = Wq2[k * 32 + c2];
#pragma unroll
      for (int i = 0; i < 8; i++) a2[i] = fmaf(sm.u[rb + i][k], wv, a2[i]);
    }
    float w3 = Wq3[c2], bb2 = bq2[c2], bb3 = bq3[0];
#pragma unroll
    for (int i = 0; i < 8; i++) {
      float u = a2[i] + bb2;
      u = (u > 0.f) ? u : expm1f(u);
      float p = u * w3;
      p += __shfl_xor(p, 1);
      p += __shfl_xor(p, 2);
      p += __shfl_xor(p, 4);
      p += __shfl_xor(p, 8);
      p += __shfl_xor(p, 16);
      int r = r0 + rb + i;
      if (c2 == 0 && r < kP) out_e[r] = p + bb3;
    }
  } else {
    // ================== node head ==================
    int r0 = (blockIdx.x - kEheadBlk) * 64;
    const unsigned short* ga = &h_bf[(size_t)(r0 + sr) * kD1 + skc * 8];
    const unsigned short* gb = &Wnt[(size_t)sr * kD1 + skc * 8];
    for (int k0 = 0; k0 < kD1; k0 += 32) {
      async_ld16(ga + k0, la);
      async_ld16(gb + k0, lb);
      __syncthreads();
      bf16x8 af = *(const bf16x8*)&sm.st.a[w * 16 + m_frag][quad * 8];
#pragma unroll
      for (int c = 0; c < 4; c++) {
        bf16x8 bfr = *(const bf16x8*)&sm.st.b[c * 16 + m_frag][quad * 8];
        acc[c] = __builtin_amdgcn_mfma_f32_16x16x32_bf16(af, bfr, acc[c], 0, 0, 0);
      }
      __syncthreads();
    }

#pragma unroll
    for (int c = 0; c < 4; c++) {
      int col = c * 16 + m_frag;
      float bv = bn1[col];
#pragma unroll
      for (int i = 0; i < 4; i++) {
        float u = acc[c][i] + bv;
        u = (u > 0.f) ? u : expm1f(u);
        sm.u[w * 16 + quad * 4 + i][col] = u;
      }
    }
    __syncthreads();

    int c2 = tid & 31, rb = (tid >> 5) * 8;
    float a2[8];
#pragma unroll
    for (int i = 0; i < 8; i++) a2[i] = 0.f;
    for (int k = 0; k < 64; k++) {
      float wv = Wn2[k * 32 + c2];
#pragma unroll
      for (int i = 0; i < 8; i++) a2[i] = fmaf(sm.u[rb + i][k], wv, a2[i]);
    }
    float w3 = Wn3[c2], bb2 = bn2[c2], bb3 = bn3[0];
#pragma unroll
    for (int i = 0; i < 8; i++) {
      float u = a2[i] + bb2;
      u = (u > 0.f) ? u : expm1f(u);
      float p = u * w3;
      p += __shfl_xor(p, 1);
      p += __shfl_xor(p, 2);
      p += __shfl_xor(p, 4);
      p += __shfl_xor(p, 8);
      p += __shfl_xor(p, 16);
      int r = r0 + rb + i;
      if (c2 == 0 && r < kN) out_n[r] = p + bb3;
    }
  }
}

// ---------------- launch ----------------
extern "C" void kernel_launch(void* const* d_in, const int* in_sizes, int n_in,
                              void* d_out, int out_size, void* d_ws, size_t ws_size,
                              hipStream_t stream) {
  const float* x          = (const float*)d_in[0];
  const int*   edge_index = (const int*)d_in[1];
  const float* edge_attr  = (const float*)d_in[2];
  const int*   pe         = (const int*)d_in[3];
  const float* Wl1 = (const float*)d_in[4];
  const float* bl1 = (const float*)d_in[5];
  const float* Wr1 = (const float*)d_in[6];
  const float* br1 = (const float*)d_in[7];
  const float* We1 = (const float*)d_in[8];
  const float* att1= (const float*)d_in[9];
  const float* b1  = (const float*)d_in[10];
  const float* Wl2 = (const float*)d_in[11];
  const float* bl2 = (const float*)d_in[12];
  const float* Wr2 = (const float*)d_in[13];
  const float* br2 = (const float*)d_in[14];
  const float* We2 = (const float*)d_in[15];
  const float* att2= (const float*)d_in[16];
  const float* b2  = (const float*)d_in[17];
  const float* Wq1 = (const float*)d_in[18];
  const float* bq1 = (const float*)d_in[19];
  const float* Wq2 = (const float*)d_in[20];
  const float* bq2 = (const float*)d_in[21];
  const float* Wq3 = (const float*)d_in[22];
  const float* bq3 = (const float*)d_in[23];
  const float* Wn1 = (const float*)d_in[24];
  const float* bn1 = (const float*)d_in[25];
  const float* Wn2 = (const float*)d_in[26];
  const float* bn2 = (const float*)d_in[27];
  const float* Wn3 = (const float*)d_in[28];
  const float* bn3 = (const float*)d_in[29];

  const int* src = edge_index;
  const int* dst = edge_index + kE;

  char* ws = (char*)d_ws;
  size_t off = 0;
  auto alloc = [&](size_t bytes) -> char* {
    char* p = ws + off;
    off += (bytes + 255) & ~(size_t)255;
    return p;
  };
  unsigned short* xl_bf = (unsigned short*)alloc((size_t)kN * kD1 * 2);
  float* xr             = (float*)alloc((size_t)kN * kD1 * 4);
  unsigned short* h_bf  = (unsigned short*)alloc((size_t)kN * kD1 * 2);
  unsigned short* Wl2t  = (unsigned short*)alloc((size_t)kD1 * kD1 * 2);
  unsigned short* Wr2t  = (unsigned short*)alloc((size_t)kD1 * kD1 * 2);
  unsigned short* Wq1t  = (unsigned short*)alloc((size_t)64 * kEFSP * 2);
  unsigned short* Wn1t  = (unsigned short*)alloc((size_t)64 * kD1 * 2);
  int* row_ptr    = (int*)alloc((kN + 1) * 4);
  int* cursor     = (int*)alloc(kN * 4);
  float4* rec     = (float4*)alloc((size_t)kE * 16);
  // counts + tbl adjacent: ONE 0xFF memset covers both (counts start at -1)
  int* counts     = (int*)alloc(kN * 4);
  unsigned* tbl   = (unsigned*)alloc((size_t)kTblSize * 2 * 4);
  size_t initBytes = ((char*)tbl - (char*)counts) + (size_t)kTblSize * 2 * 4;

  hipMemsetAsync(counts, 0xFF, initBytes, stream);

  // mega kernel 1: layer-1 dual projection + histogram/hash + weight converts
  mega1_k<<<kMegaBlk, 256, 0, stream>>>(x, Wl1, bl1, Wr1, br1, xl_bf, xr,
                                        src, dst, counts, tbl,
                                        Wl2, Wr2, Wq1, Wn1,
                                        Wl2t, Wr2t, Wq1t, Wn1t);
  scan_k<<<1, 1024, 0, stream>>>(counts, row_ptr, cursor);
  scatter_k<<<(kE + 255) / 256, 256, 0, stream>>>(src, dst, edge_attr, cursor, rec);

  gat_k<<<kN, 256, 0, stream>>>(xl_bf, xr, row_ptr, rec, We1, att1, b1, h_bf);
  mgemm_k<0, 1, 0><<<dim3(kGemmBX, 8), 256, 0, stream>>>(h_bf, kN, kD1,
                                                         Wl2t, bl2, xl_bf,
                                                         Wr2t, br2, xr, kD1, 4);
  gat_k<<<kN, 256, 0, stream>>>(xl_bf, xr, row_ptr, rec, We2, att2, b2, h_bf);

  heads_k<<<kEheadBlk + kNheadBlk, 256, 0, stream>>>(h_bf, pe, edge_attr, tbl,
                                                     Wq1t, bq1, Wq2, bq2, Wq3, bq3,
                                                     Wn1t, bn1, Wn2, bn2, Wn3, bn3,
                                                     (float*)d_out, (float*)d_out + kP);
}

// Round 9
// 263.349 us; speedup vs baseline: 1.0149x; 1.0149x over previous
//
#include <hip/hip_runtime.h>
#include <cmath>

// ---------------- problem constants ----------------
constexpr int kN  = 10000;   // nodes
constexpr int kE  = 160000;  // edges
constexpr int kP  = 4000;    // physical edges
constexpr int kND = 8;       // input node feat dim
constexpr int kH  = 4;       // heads
constexpr int kC  = 64;      // channels per head
constexpr int kD1 = kH * kC; // 256
constexpr int kEFS  = 2 * kD1 + 3; // 515 real concat dim
constexpr int kEFSP = 544;         // padded to 17*32 for BK=32 MFMA loop

constexpr unsigned kTblSize = 1u << 19;
constexpr unsigned kTblMask = kTblSize - 1;
constexpr unsigned kEmpty   = 0xFFFFFFFFu;

typedef __attribute__((ext_vector_type(8))) short bf16x8;
typedef __attribute__((ext_vector_type(4))) float f32x4;

__device__ __forceinline__ unsigned short f2bf(float f) {
  unsigned u = __float_as_uint(f);
  unsigned r = (u + 0x7FFFu + ((u >> 16) & 1u)) >> 16;
  return (unsigned short)r;
}
__device__ __forceinline__ float bf2f(unsigned short u) {
  return __uint_as_float(((unsigned)u) << 16);
}

__device__ __forceinline__ unsigned hash_u32(unsigned k) {
  k *= 2654435761u;
  k ^= k >> 16;
  return k & kTblMask;
}

// ---------------- mega kernel 1: layer1 dual proj + hist/hash + weight cvt
constexpr int kGemmBX    = (kN + 63) / 64;       // 157
constexpr int kGemmBlk   = kGemmBX * 8;          // 1256
constexpr int kHistBlk   = (kE + 255) / 256;     // 625
constexpr int kCvtElems  = 2 * 256 * 256 + 64 * kEFSP + 64 * 256; // 182272
constexpr int kCvtBlk    = (kCvtElems + 255) / 256; // 712
constexpr int kMegaBlk   = kGemmBlk + kHistBlk + kCvtBlk;

__launch_bounds__(256)
__global__ void mega1_k(const float* __restrict__ x,
                        const float* __restrict__ Wl1, const float* __restrict__ bl1,
                        const float* __restrict__ Wr1, const float* __restrict__ br1,
                        unsigned short* __restrict__ xl_bf, unsigned short* __restrict__ xr_bf,
                        const int* __restrict__ src, const int* __restrict__ dst,
                        int* __restrict__ counts, unsigned* __restrict__ tbl,
                        const float* __restrict__ Wl2, const float* __restrict__ Wr2,
                        const float* __restrict__ Wq1, const float* __restrict__ Wn1,
                        unsigned short* __restrict__ Wl2t, unsigned short* __restrict__ Wr2t,
                        unsigned short* __restrict__ Wq1t, unsigned short* __restrict__ Wn1t) {
  __shared__ __align__(16) float s_a[8][68];
  __shared__ __align__(16) float s_w[8][64];
  int bi = blockIdx.x;
  int tid = threadIdx.x;
  if (bi < kGemmBlk) {
    // ---- layer-1 dual projection, K=8; both outputs bf16 ----
    int bx = bi % kGemmBX, by = bi / kGemmBX;
    int r0 = bx * 64;
    const float* W; const float* bb; unsigned short* outp;
    if (by < 4) { W = Wl1; bb = bl1; outp = xl_bf; }
    else        { W = Wr1; bb = br1; outp = xr_bf; by -= 4; }
    int cbase = by * 64;
#pragma unroll
    for (int f = tid; f < 512; f += 256) { // A: 64 rows x 8 k (coalesced)
      int rr = f >> 3, kk = f & 7;
      int r = r0 + rr;
      s_a[kk][rr] = (r < kN) ? x[(size_t)r * kND + kk] : 0.f;
    }
#pragma unroll
    for (int f = tid; f < 512; f += 256) { // W: 8 k x 64 cols
      int kk = f >> 6, cc = f & 63;
      s_w[kk][cc] = W[(size_t)kk * kD1 + cbase + cc];
    }
    __syncthreads();
    int tx = tid & 15, ty = tid >> 4;
    float acc[4][4];
#pragma unroll
    for (int i = 0; i < 4; i++)
#pragma unroll
      for (int j = 0; j < 4; j++) acc[i][j] = 0.f;
#pragma unroll
    for (int kk = 0; kk < 8; kk++) {
      float4 av = *(const float4*)&s_a[kk][ty * 4];
      float4 wv = *(const float4*)&s_w[kk][tx * 4];
      float a4[4] = {av.x, av.y, av.z, av.w};
      float w4[4] = {wv.x, wv.y, wv.z, wv.w};
#pragma unroll
      for (int i = 0; i < 4; i++)
#pragma unroll
        for (int j = 0; j < 4; j++) acc[i][j] = fmaf(a4[i], w4[j], acc[i][j]);
    }
    int c = cbase + tx * 4;
    float b4[4] = {bb[c], bb[c + 1], bb[c + 2], bb[c + 3]};
#pragma unroll
    for (int i = 0; i < 4; i++) {
      int r = r0 + ty * 4 + i;
      if (r < kN) {
        ushort4 v;
        v.x = f2bf(acc[i][0] + b4[0]); v.y = f2bf(acc[i][1] + b4[1]);
        v.z = f2bf(acc[i][2] + b4[2]); v.w = f2bf(acc[i][3] + b4[3]);
        *(ushort4*)&outp[(size_t)r * kD1 + c] = v;
      }
    }
  } else if (bi < kGemmBlk + kHistBlk) {
    // ---- histogram (counts init -1 via 0xFF memset) + hash insert ----
    int e = (bi - kGemmBlk) * 256 + tid;
    if (e >= kE) return;
    int d = dst[e];
    atomicAdd(&counts[d], 1);
    unsigned key = (unsigned)src[e] * (unsigned)kN + (unsigned)d;
    unsigned h = hash_u32(key);
    for (;;) {
      unsigned prev = atomicCAS(&tbl[2 * h], kEmpty, key);
      if (prev == kEmpty || prev == key) {
        atomicMin(&tbl[2 * h + 1], (unsigned)e);
        return;
      }
      h = (h + 1) & kTblMask;
    }
  } else {
    // ---- weight transpose + fp32->bf16 ----
    const int s0 = 256 * 256, s1 = 2 * s0, s2 = s1 + 64 * kEFSP, s3 = s2 + 64 * 256;
    int idx = (bi - kGemmBlk - kHistBlk) * 256 + tid;
    if (idx < s0) {
      int n = idx >> 8, k = idx & 255;
      Wl2t[idx] = f2bf(Wl2[(size_t)k * 256 + n]);
    } else if (idx < s1) {
      int q = idx - s0;
      int n = q >> 8, k = q & 255;
      Wr2t[q] = f2bf(Wr2[(size_t)k * 256 + n]);
    } else if (idx < s2) {
      int q = idx - s1;
      int n = q / kEFSP, k = q - n * kEFSP;
      Wq1t[q] = (k < kEFS) ? f2bf(Wq1[(size_t)k * 64 + n]) : (unsigned short)0;
    } else if (idx < s3) {
      int q = idx - s2;
      int n = q >> 8, k = q & 255;
      Wn1t[q] = f2bf(Wn1[(size_t)k * 64 + n]);
    }
  }
}

// ---------------- single-block exclusive scan: 1024 thr x 10 counts each ---
__launch_bounds__(1024)
__global__ void scan_k(const int* __restrict__ counts, int* __restrict__ row_ptr,
                       int* __restrict__ cursor) {
  __shared__ int wsum[16];
  int tid = threadIdx.x;
  int lane = tid & 63, w = tid >> 6;
  int base = tid * 10;
  int v[10];
  int tot = 0;
#pragma unroll
  for (int i = 0; i < 10; i++) {
    int idx = base + i;
    v[i] = (idx < kN) ? (counts[idx] + 1) : 0; // +1: counts init was -1
    tot += v[i];
  }
  int inc = tot;
#pragma unroll
  for (int o = 1; o < 64; o <<= 1) {
    int t = __shfl_up(inc, o);
    if (lane >= o) inc += t;
  }
  if (lane == 63) wsum[w] = inc;
  __syncthreads();
  int woff = 0;
  for (int q = 0; q < w; q++) woff += wsum[q];
  int run = woff + inc - tot;
#pragma unroll
  for (int i = 0; i < 10; i++) {
    int idx = base + i;
    if (idx < kN) { row_ptr[idx] = run; cursor[idx] = run; }
    run += v[i];
  }
  if (tid == 0) row_ptr[kN] = kE;
}

// scatter edge records {src, ea0, ea1, ea2} into CSR-by-dst order
__global__ void scatter_k(const int* __restrict__ src, const int* __restrict__ dst,
                          const float* __restrict__ edge_attr,
                          int* __restrict__ cursor, float4* __restrict__ rec) {
  int e = blockIdx.x * blockDim.x + threadIdx.x;
  if (e >= kE) return;
  int d = dst[e];
  int pos = atomicAdd(&cursor[d], 1);
  float4 r;
  r.x = __int_as_float(src[e]);
  r.y = edge_attr[e * 3 + 0];
  r.z = edge_attr[e * 3 + 1];
  r.w = edge_attr[e * 3 + 2];
  rec[pos] = r;
}

// ---------------- bf16 MFMA GEMM (layer-2 dual projection, both out bf16) --
template <int ACT>
__launch_bounds__(256)
__global__ void mgemm_k(const unsigned short* __restrict__ in, int M, int Kp,
                        const unsigned short* __restrict__ Wt0,
                        const float* __restrict__ b0, unsigned short* __restrict__ out0,
                        const unsigned short* __restrict__ Wt1,
                        const float* __restrict__ b1, unsigned short* __restrict__ out1,
                        int N, int nby) {
  __shared__ __align__(16) short s_a[64][32];
  __shared__ __align__(16) short s_b[64][32];
  int tid = threadIdx.x;
  int l = tid & 63, w = tid >> 6;
  int r0 = blockIdx.x * 64;
  int by = blockIdx.y;
  const unsigned short* Wt = Wt0; const float* bb = b0; unsigned short* outv = out0;
  if (by >= nby) { Wt = Wt1; bb = b1; outv = out1; by -= nby; }
  int cbase = by * 64;

  int sr = tid >> 2;
  int skc = tid & 3;

  f32x4 acc[4];
#pragma unroll
  for (int c = 0; c < 4; c++) acc[c] = (f32x4){0.f, 0.f, 0.f, 0.f};

  int m_frag = l & 15, quad = l >> 4;

  for (int k0 = 0; k0 < Kp; k0 += 32) {
    bf16x8 av = {0, 0, 0, 0, 0, 0, 0, 0};
    int r = r0 + sr;
    if (r < M) av = *(const bf16x8*)&in[(size_t)r * Kp + k0 + skc * 8];
    *(bf16x8*)&s_a[sr][skc * 8] = av;
    bf16x8 bv = *(const bf16x8*)&Wt[(size_t)(cbase + sr) * Kp + k0 + skc * 8];
    *(bf16x8*)&s_b[sr][skc * 8] = bv;
    __syncthreads();
    bf16x8 af = *(const bf16x8*)&s_a[w * 16 + m_frag][quad * 8];
#pragma unroll
    for (int c = 0; c < 4; c++) {
      bf16x8 bfr = *(const bf16x8*)&s_b[c * 16 + m_frag][quad * 8];
      acc[c] = __builtin_amdgcn_mfma_f32_16x16x32_bf16(af, bfr, acc[c], 0, 0, 0);
    }
    __syncthreads();
  }

#pragma unroll
  for (int c = 0; c < 4; c++) {
    int col = cbase + c * 16 + m_frag;
    float bv = bb[col];
#pragma unroll
    for (int i = 0; i < 4; i++) {
      int r = r0 + w * 16 + quad * 4 + i;
      if (r < M) {
        float u = acc[c][i] + bv;
        if (ACT == 1) u = (u > 0.f) ? u : expm1f(u);
        outv[(size_t)r * N + col] = f2bf(u);
      }
    }
  }
}

// ---------------- GATv2 layer: block = node, 4 waves split the edge list ---
__launch_bounds__(256)
__global__ void gat_k(const unsigned short* __restrict__ xl_bf,
                      const unsigned short* __restrict__ xr_bf,
                      const int* __restrict__ row_ptr, const float4* __restrict__ rec,
                      const float* __restrict__ We, const float* __restrict__ att,
                      const float* __restrict__ bias, unsigned short* __restrict__ out_bf) {
  __shared__ float sA[4][4][64]; // [wave][channel][lane] - conflict-free
  __shared__ float sS[4][64];
  int n = blockIdx.x;
  int tid = threadIdx.x;
  int l = tid & 63, w = tid >> 6;
  int c0 = (l >> 4) * kC + (l & 15) * 4;

  ushort4 xrv = *(const ushort4*)&xr_bf[(size_t)n * kD1 + c0];
  float4 xr_c = {bf2f(xrv.x), bf2f(xrv.y), bf2f(xrv.z), bf2f(xrv.w)};
  float4 we0 = *(const float4*)&We[0 * kD1 + c0];
  float4 we1 = *(const float4*)&We[1 * kD1 + c0];
  float4 we2 = *(const float4*)&We[2 * kD1 + c0];
  float4 at4 = *(const float4*)&att[c0];

  int row = row_ptr[n], end = row_ptr[n + 1];
  float S = 0.f;
  float A0 = 0.f, A1 = 0.f, A2 = 0.f, A3 = 0.f;

  // 2-deep software pipeline over this wave's edge subset (stride 4)
  int k = row + w;
  float4 rA, rB; ushort4 xA, xB;
  if (k < end) {
    rA = rec[k];
    xA = *(const ushort4*)&xl_bf[(size_t)__float_as_int(rA.x) * kD1 + c0];
  }
  if (k + 4 < end) {
    rB = rec[k + 4];
    xB = *(const ushort4*)&xl_bf[(size_t)__float_as_int(rB.x) * kD1 + c0];
  }
  for (; k < end; k += 4) {
    float4 rc = rA; ushort4 xc = xA;
    rA = rB; xA = xB;
    if (k + 8 < end) {
      rB = rec[k + 8];
      xB = *(const ushort4*)&xl_bf[(size_t)__float_as_int(rB.x) * kD1 + c0];
    }
    float x0 = bf2f(xc.x), x1 = bf2f(xc.y), x2 = bf2f(xc.z), x3 = bf2f(xc.w);
    float m0 = x0 + xr_c.x + fmaf(rc.y, we0.x, fmaf(rc.z, we1.x, rc.w * we2.x));
    float m1 = x1 + xr_c.y + fmaf(rc.y, we0.y, fmaf(rc.z, we1.y, rc.w * we2.y));
    float m2 = x2 + xr_c.z + fmaf(rc.y, we0.z, fmaf(rc.z, we1.z, rc.w * we2.z));
    float m3 = x3 + xr_c.w + fmaf(rc.y, we0.w, fmaf(rc.z, we1.w, rc.w * we2.w));
    m0 = fmaxf(m0, 0.2f * m0); m1 = fmaxf(m1, 0.2f * m1);
    m2 = fmaxf(m2, 0.2f * m2); m3 = fmaxf(m3, 0.2f * m3);
    float t = fmaf(m0, at4.x, fmaf(m1, at4.y, fmaf(m2, at4.z, m3 * at4.w)));
    t += __shfl_xor(t, 1);
    t += __shfl_xor(t, 2);
    t += __shfl_xor(t, 4);
    t += __shfl_xor(t, 8); // reduce within 16-lane head group
    float wgt = __expf(t); // logits O(1): no max-subtraction needed
    S += wgt;
    A0 = fmaf(wgt, x0, A0); A1 = fmaf(wgt, x1, A1);
    A2 = fmaf(wgt, x2, A2); A3 = fmaf(wgt, x3, A3);
  }
  sA[w][0][l] = A0; sA[w][1][l] = A1; sA[w][2][l] = A2; sA[w][3][l] = A3;
  sS[w][l] = S;
  __syncthreads();
  if (w == 0) {
    float St = sS[0][l] + sS[1][l] + sS[2][l] + sS[3][l];
    float T0 = sA[0][0][l] + sA[1][0][l] + sA[2][0][l] + sA[3][0][l];
    float T1 = sA[0][1][l] + sA[1][1][l] + sA[2][1][l] + sA[3][1][l];
    float T2 = sA[0][2][l] + sA[1][2][l] + sA[2][2][l] + sA[3][2][l];
    float T3 = sA[0][3][l] + sA[1][3][l] + sA[2][3][l] + sA[3][3][l];
    float inv = 1.f / (St + 1e-16f);
    float4 b4 = *(const float4*)&bias[c0];
    float u0 = fmaf(T0, inv, b4.x), u1 = fmaf(T1, inv, b4.y);
    float u2 = fmaf(T2, inv, b4.z), u3 = fmaf(T3, inv, b4.w);
    u0 = (u0 > 0.f) ? u0 : expm1f(u0);
    u1 = (u1 > 0.f) ? u1 : expm1f(u1);
    u2 = (u2 > 0.f) ? u2 : expm1f(u2);
    u3 = (u3 > 0.f) ? u3 : expm1f(u3);
    ushort4 ov;
    ov.x = f2bf(u0); ov.y = f2bf(u1); ov.z = f2bf(u2); ov.w = f2bf(u3);
    *(ushort4*)&out_bf[(size_t)n * kD1 + c0] = ov;
  }
}

// ---------------- fused heads: edge head blocks then node head blocks ------
constexpr int kEheadBlk = (kP + 63) / 64; // 63
constexpr int kNheadBlk = (kN + 63) / 64; // 157

__launch_bounds__(256)
__global__ void heads_k(const unsigned short* __restrict__ h_bf, const int* __restrict__ pe,
                        const float* __restrict__ edge_attr, const unsigned* __restrict__ tbl,
                        const unsigned short* __restrict__ Wqt, const float* __restrict__ bq1,
                        const float* __restrict__ Wq2, const float* __restrict__ bq2,
                        const float* __restrict__ Wq3, const float* __restrict__ bq3,
                        const unsigned short* __restrict__ Wnt, const float* __restrict__ bn1,
                        const float* __restrict__ Wn2, const float* __restrict__ bn2,
                        const float* __restrict__ Wn3, const float* __restrict__ bn3,
                        float* __restrict__ out_e, float* __restrict__ out_n) {
  __shared__ union {
    struct { short a[64][32]; short b[64][32]; } st;
    float u[64][65];
  } sm;
  __shared__ int s_i[64], s_j[64];
  __shared__ unsigned short s_ea[64][4];
  int tid = threadIdx.x;
  int l = tid & 63, w = tid >> 6;
  int sr = tid >> 2, skc = tid & 3;
  int m_frag = l & 15, quad = l >> 4;

  f32x4 acc[4];
#pragma unroll
  for (int c = 0; c < 4; c++) acc[c] = (f32x4){0.f, 0.f, 0.f, 0.f};

  if (blockIdx.x < kEheadBlk) {
    // ================== edge head ==================
    int r0 = blockIdx.x * 64;
    if (tid < 64) {
      int p = r0 + tid;
      int i = 0, j = 0;
      unsigned short e0 = 0, e1 = 0, e2 = 0;
      if (p < kP) {
        i = pe[p * 2 + 0]; j = pe[p * 2 + 1];
        unsigned best = kEmpty;
        unsigned keys[2] = { (unsigned)i * (unsigned)kN + (unsigned)j,
                             (unsigned)j * (unsigned)kN + (unsigned)i };
        for (int q = 0; q < 2; q++) {
          unsigned key = keys[q];
          unsigned hsh = hash_u32(key);
          for (;;) {
            unsigned k2 = tbl[2 * hsh];
            if (k2 == kEmpty) break;
            if (k2 == key) {
              unsigned v = tbl[2 * hsh + 1];
              if (v < best) best = v;
              break;
            }
            hsh = (hsh + 1) & kTblMask;
          }
        }
        if (best != kEmpty) {
          e0 = f2bf(edge_attr[best * 3 + 0]);
          e1 = f2bf(edge_attr[best * 3 + 1]);
          e2 = f2bf(edge_attr[best * 3 + 2]);
        }
      }
      s_i[tid] = i; s_j[tid] = j;
      s_ea[tid][0] = e0; s_ea[tid][1] = e1; s_ea[tid][2] = e2; s_ea[tid][3] = 0;
    }
    __syncthreads();

    for (int k0 = 0; k0 < kEFSP; k0 += 32) {
      int gk = k0 + skc * 8;
      bf16x8 av;
      if (gk < 256) {
        av = *(const bf16x8*)&h_bf[(size_t)s_i[sr] * kD1 + gk];
      } else if (gk < 512) {
        av = *(const bf16x8*)&h_bf[(size_t)s_j[sr] * kD1 + (gk - 256)];
      } else {
        av = (bf16x8){0, 0, 0, 0, 0, 0, 0, 0};
        if (gk == 512) {
          av[0] = (short)s_ea[sr][0];
          av[1] = (short)s_ea[sr][1];
          av[2] = (short)s_ea[sr][2];
        }
      }
      *(bf16x8*)&sm.st.a[sr][skc * 8] = av;
      bf16x8 bv = *(const bf16x8*)&Wqt[(size_t)sr * kEFSP + k0 + skc * 8];
      *(bf16x8*)&sm.st.b[sr][skc * 8] = bv;
      __syncthreads();
      bf16x8 af = *(const bf16x8*)&sm.st.a[w * 16 + m_frag][quad * 8];
#pragma unroll
      for (int c = 0; c < 4; c++) {
        bf16x8 bfr = *(const bf16x8*)&sm.st.b[c * 16 + m_frag][quad * 8];
        acc[c] = __builtin_amdgcn_mfma_f32_16x16x32_bf16(af, bfr, acc[c], 0, 0, 0);
      }
      __syncthreads();
    }

#pragma unroll
    for (int c = 0; c < 4; c++) {
      int col = c * 16 + m_frag;
      float bv = bq1[col];
#pragma unroll
      for (int i = 0; i < 4; i++) {
        float u = acc[c][i] + bv;
        u = (u > 0.f) ? u : expm1f(u);
        sm.u[w * 16 + quad * 4 + i][col] = u;
      }
    }
    __syncthreads();

    int c2 = tid & 31, rb = (tid >> 5) * 8;
    float a2[8];
#pragma unroll
    for (int i = 0; i < 8; i++) a2[i] = 0.f;
    for (int k = 0; k < 64; k++) {
      float wv = Wq2[k * 32 + c2];
#pragma unroll
      for (int i = 0; i < 8; i++) a2[i] = fmaf(sm.u[rb + i][k], wv, a2[i]);
    }
    float w3 = Wq3[c2], bb2 = bq2[c2], bb3 = bq3[0];
#pragma unroll
    for (int i = 0; i < 8; i++) {
      float u = a2[i] + bb2;
      u = (u > 0.f) ? u : expm1f(u);
      float p = u * w3;
      p += __shfl_xor(p, 1);
      p += __shfl_xor(p, 2);
      p += __shfl_xor(p, 4);
      p += __shfl_xor(p, 8);
      p += __shfl_xor(p, 16);
      int r = r0 + rb + i;
      if (c2 == 0 && r < kP) out_e[r] = p + bb3;
    }
  } else {
    // ================== node head ==================
    int r0 = (blockIdx.x - kEheadBlk) * 64;
    for (int k0 = 0; k0 < kD1; k0 += 32) {
      bf16x8 av = {0, 0, 0, 0, 0, 0, 0, 0};
      int r = r0 + sr;
      if (r < kN) av = *(const bf16x8*)&h_bf[(size_t)r * kD1 + k0 + skc * 8];
      *(bf16x8*)&sm.st.a[sr][skc * 8] = av;
      bf16x8 bv = *(const bf16x8*)&Wnt[(size_t)sr * kD1 + k0 + skc * 8];
      *(bf16x8*)&sm.st.b[sr][skc * 8] = bv;
      __syncthreads();
      bf16x8 af = *(const bf16x8*)&sm.st.a[w * 16 + m_frag][quad * 8];
#pragma unroll
      for (int c = 0; c < 4; c++) {
        bf16x8 bfr = *(const bf16x8*)&sm.st.b[c * 16 + m_frag][quad * 8];
        acc[c] = __builtin_amdgcn_mfma_f32_16x16x32_bf16(af, bfr, acc[c], 0, 0, 0);
      }
      __syncthreads();
    }

#pragma unroll
    for (int c = 0; c < 4; c++) {
      int col = c * 16 + m_frag;
      float bv = bn1[col];
#pragma unroll
      for (int i = 0; i < 4; i++) {
        float u = acc[c][i] + bv;
        u = (u > 0.f) ? u : expm1f(u);
        sm.u[w * 16 + quad * 4 + i][col] = u;
      }
    }
    __syncthreads();

    int c2 = tid & 31, rb = (tid >> 5) * 8;
    float a2[8];
#pragma unroll
    for (int i = 0; i < 8; i++) a2[i] = 0.f;
    for (int k = 0; k < 64; k++) {
      float wv = Wn2[k * 32 + c2];
#pragma unroll
      for (int i = 0; i < 8; i++) a2[i] = fmaf(sm.u[rb + i][k], wv, a2[i]);
    }
    float w3 = Wn3[c2], bb2 = bn2[c2], bb3 = bn3[0];
#pragma unroll
    for (int i = 0; i < 8; i++) {
      float u = a2[i] + bb2;
      u = (u > 0.f) ? u : expm1f(u);
      float p = u * w3;
      p += __shfl_xor(p, 1);
      p += __shfl_xor(p, 2);
      p += __shfl_xor(p, 4);
      p += __shfl_xor(p, 8);
      p += __shfl_xor(p, 16);
      int r = r0 + rb + i;
      if (c2 == 0 && r < kN) out_n[r] = p + bb3;
    }
  }
}

// ---------------- launch ----------------
extern "C" void kernel_launch(void* const* d_in, const int* in_sizes, int n_in,
                              void* d_out, int out_size, void* d_ws, size_t ws_size,
                              hipStream_t stream) {
  const float* x          = (const float*)d_in[0];
  const int*   edge_index = (const int*)d_in[1];
  const float* edge_attr  = (const float*)d_in[2];
  const int*   pe         = (const int*)d_in[3];
  const float* Wl1 = (const float*)d_in[4];
  const float* bl1 = (const float*)d_in[5];
  const float* Wr1 = (const float*)d_in[6];
  const float* br1 = (const float*)d_in[7];
  const float* We1 = (const float*)d_in[8];
  const float* att1= (const float*)d_in[9];
  const float* b1  = (const float*)d_in[10];
  const float* Wl2 = (const float*)d_in[11];
  const float* bl2 = (const float*)d_in[12];
  const float* Wr2 = (const float*)d_in[13];
  const float* br2 = (const float*)d_in[14];
  const float* We2 = (const float*)d_in[15];
  const float* att2= (const float*)d_in[16];
  const float* b2  = (const float*)d_in[17];
  const float* Wq1 = (const float*)d_in[18];
  const float* bq1 = (const float*)d_in[19];
  const float* Wq2 = (const float*)d_in[20];
  const float* bq2 = (const float*)d_in[21];
  const float* Wq3 = (const float*)d_in[22];
  const float* bq3 = (const float*)d_in[23];
  const float* Wn1 = (const float*)d_in[24];
  const float* bn1 = (const float*)d_in[25];
  const float* Wn2 = (const float*)d_in[26];
  const float* bn2 = (const float*)d_in[27];
  const float* Wn3 = (const float*)d_in[28];
  const float* bn3 = (const float*)d_in[29];

  const int* src = edge_index;
  const int* dst = edge_index + kE;

  char* ws = (char*)d_ws;
  size_t off = 0;
  auto alloc = [&](size_t bytes) -> char* {
    char* p = ws + off;
    off += (bytes + 255) & ~(size_t)255;
    return p;
  };
  unsigned short* xl_bf = (unsigned short*)alloc((size_t)kN * kD1 * 2);
  unsigned short* xr_bf = (unsigned short*)alloc((size_t)kN * kD1 * 2);
  unsigned short* h_bf  = (unsigned short*)alloc((size_t)kN * kD1 * 2);
  unsigned short* Wl2t  = (unsigned short*)alloc((size_t)kD1 * kD1 * 2);
  unsigned short* Wr2t  = (unsigned short*)alloc((size_t)kD1 * kD1 * 2);
  unsigned short* Wq1t  = (unsigned short*)alloc((size_t)64 * kEFSP * 2);
  unsigned short* Wn1t  = (unsigned short*)alloc((size_t)64 * kD1 * 2);
  int* row_ptr    = (int*)alloc((kN + 1) * 4);
  int* cursor     = (int*)alloc(kN * 4);
  float4* rec     = (float4*)alloc((size_t)kE * 16);
  // counts + tbl adjacent: ONE 0xFF memset covers both (counts start at -1)
  int* counts     = (int*)alloc(kN * 4);
  unsigned* tbl   = (unsigned*)alloc((size_t)kTblSize * 2 * 4);
  size_t initBytes = ((char*)tbl - (char*)counts) + (size_t)kTblSize * 2 * 4;

  hipMemsetAsync(counts, 0xFF, initBytes, stream);

  // mega kernel 1: layer-1 dual projection + histogram/hash + weight converts
  mega1_k<<<kMegaBlk, 256, 0, stream>>>(x, Wl1, bl1, Wr1, br1, xl_bf, xr_bf,
                                        src, dst, counts, tbl,
                                        Wl2, Wr2, Wq1, Wn1,
                                        Wl2t, Wr2t, Wq1t, Wn1t);
  scan_k<<<1, 1024, 0, stream>>>(counts, row_ptr, cursor);
  scatter_k<<<(kE + 255) / 256, 256, 0, stream>>>(src, dst, edge_attr, cursor, rec);

  gat_k<<<kN, 256, 0, stream>>>(xl_bf, xr_bf, row_ptr, rec, We1, att1, b1, h_bf);
  mgemm_k<0><<<dim3(kGemmBX, 8), 256, 0, stream>>>(h_bf, kN, kD1,
                                                   Wl2t, bl2, xl_bf,
                                                   Wr2t, br2, xr_bf, kD1, 4);
  gat_k<<<kN, 256, 0, stream>>>(xl_bf, xr_bf, row_ptr, rec, We2, att2, b2, h_bf);

  heads_k<<<kEheadBlk + kNheadBlk, 256, 0, stream>>>(h_bf, pe, edge_attr, tbl,
                                                     Wq1t, bq1, Wq2, bq2, Wq3, bq3,
                                                     Wn1t, bn1, Wn2, bn2, Wn3, bn3,
                                                     (float*)d_out, (float*)d_out + kP);
}